// Round 2
// baseline (910.609 us; speedup 1.0000x reference)
//
#include <hip/hip_runtime.h>

typedef float v2f __attribute__((ext_vector_type(2)));

#define B_   32
#define DE_  256
#define T_   32
#define C_   128
#define HW_  16384

__device__ inline v2f vfma2(v2f a, v2f b, v2f c) {
#if __has_builtin(__builtin_elementwise_fma)
    return __builtin_elementwise_fma(a, b, c);
#else
    v2f r; r.x = fmaf(a.x, b.x, c.x); r.y = fmaf(a.y, b.y, c.y); return r;
#endif
}

// Kernel 1: e_[b][c][t] = sum_d e[b][d][t] * Wd[d][c] + bias[c]   (fp32 -> ws)
// grid (8, 32): blockIdx.x = 16-channel slab, blockIdx.y = batch. 256 threads.
__global__ __launch_bounds__(256) void dense_e_kernel(
    const float* __restrict__ e, const float* __restrict__ Wd,
    const float* __restrict__ bias, float* __restrict__ ews)
{
    __shared__ float elds[DE_ * T_];   // 32 KB, [d][t]
    __shared__ float wlds[DE_ * 16];   // 16 KB, [d][c_local]
    const int b   = blockIdx.y;
    const int cq  = blockIdx.x;        // channels [cq*16, cq*16+16)
    const int tid = threadIdx.x;       // owns d-row = tid

    {
        const float4* erow = (const float4*)(e + ((size_t)b * DE_ + tid) * T_);
        float4* edst = (float4*)(elds + tid * T_);
        #pragma unroll
        for (int i = 0; i < 8; ++i) edst[i] = erow[i];

        const float4* wrow = (const float4*)(Wd + (size_t)tid * C_ + cq * 16);
        float4* wdst = (float4*)(wlds + tid * 16);
        #pragma unroll
        for (int i = 0; i < 4; ++i) wdst[i] = wrow[i];
    }
    __syncthreads();

    const int t  = tid & 31;
    const int c8 = tid >> 5;           // 0..7
    float a0 = 0.f, a1 = 0.f;
    #pragma unroll 8
    for (int d = 0; d < DE_; ++d) {
        float ev = elds[d * T_ + t];
        a0 = fmaf(ev, wlds[d * 16 + c8],     a0);
        a1 = fmaf(ev, wlds[d * 16 + 8 + c8], a1);
    }
    const int c0 = cq * 16 + c8;
    a0 += bias[c0];
    a1 += bias[c0 + 8];
    ews[((size_t)b * C_ + c0)     * T_ + t] = a0;
    ews[((size_t)b * C_ + c0 + 8) * T_ + t] = a1;
}

// Kernel 2: fused scores + softmax(T) + context + concat copy.
// One thread per spatial position n. grid 2048 blocks x 256 threads.
__global__ __launch_bounds__(256) void attn_fused_kernel(
    const float* __restrict__ h,
    const float* __restrict__ ews,
    float* __restrict__ out)
{
    const int b = blockIdx.x >> 6;                        // uniform per block
    const int n = ((blockIdx.x & 63) << 8) | threadIdx.x;
    const float* __restrict__ eb = ews + (size_t)b * (C_ * T_);   // [c][t], uniform
    const float4* hrow = (const float4*)(h + ((size_t)b * HW_ + n) * C_);
    float4* orow = (float4*)(out + ((size_t)b * HW_ + n) * (2 * C_));

    v2f s2[16];
    #pragma unroll
    for (int i = 0; i < 16; ++i) s2[i] = (v2f){0.f, 0.f};

    // Pass 1: logits s[t] = sum_c e_[c][t] * h[n][c]; also copy h into concat half.
    #pragma unroll 4
    for (int cb = 0; cb < 32; ++cb) {
        float4 hv = hrow[cb];
        orow[32 + cb] = hv;                               // passthrough copy
        float hc[4] = {hv.x, hv.y, hv.z, hv.w};
        #pragma unroll
        for (int q = 0; q < 4; ++q) {
            const v2f* er = (const v2f*)(eb + (cb * 4 + q) * T_);  // uniform
            v2f hb = {hc[q], hc[q]};
            #pragma unroll
            for (int tp = 0; tp < 16; ++tp) s2[tp] = vfma2(hb, er[tp], s2[tp]);
        }
    }

    // Softmax over 32 logits — entirely thread-local.
    v2f m2 = s2[0];
    #pragma unroll
    for (int i = 1; i < 16; ++i) {
        m2.x = fmaxf(m2.x, s2[i].x);
        m2.y = fmaxf(m2.y, s2[i].y);
    }
    const float m = fmaxf(m2.x, m2.y);
    float l = 0.f;
    #pragma unroll
    for (int i = 0; i < 16; ++i) {
        v2f p;
        p.x = __expf(s2[i].x - m);
        p.y = __expf(s2[i].y - m);
        s2[i] = p;
        l += p.x + p.y;
    }
    const float inv = 1.0f / l;
    #pragma unroll
    for (int i = 0; i < 16; ++i) { s2[i].x *= inv; s2[i].y *= inv; }

    // Pass 2: context c_out[c] = sum_t e_[c][t] * beta[t]; fp32 out.
    #pragma unroll 4
    for (int cb = 0; cb < 32; ++cb) {
        float r[4];
        #pragma unroll
        for (int q = 0; q < 4; ++q) {
            const v2f* er = (const v2f*)(eb + (cb * 4 + q) * T_);
            v2f a = {0.f, 0.f};
            #pragma unroll
            for (int tp = 0; tp < 16; ++tp) a = vfma2(er[tp], s2[tp], a);
            r[q] = a.x + a.y;
        }
        float4 st = {r[0], r[1], r[2], r[3]};
        orow[cb] = st;
    }
}

extern "C" void kernel_launch(void* const* d_in, const int* in_sizes, int n_in,
                              void* d_out, int out_size, void* d_ws, size_t ws_size,
                              hipStream_t stream) {
    const float* e    = (const float*)d_in[0];   // [B, DE, T]
    const float* h    = (const float*)d_in[1];   // [B, H, W, C]
    const float* Wd   = (const float*)d_in[2];   // [DE, C]
    const float* bias = (const float*)d_in[3];   // [C]
    float* ews = (float*)d_ws;                   // [B, C, T] fp32 (512 KB scratch)
    float* out = (float*)d_out;                  // [B, H, W, 2C] fp32

    dense_e_kernel<<<dim3(8, 32), 256, 0, stream>>>(e, Wd, bias, ews);
    attn_fused_kernel<<<dim3(32 * (HW_ / 256)), 256, 0, stream>>>(h, ews, out);
}